// Round 7
// baseline (352.191 us; speedup 1.0000x reference)
//
#include <hip/hip_runtime.h>
#include <hip/hip_bf16.h>
#include <stdint.h>

// Problem constants (shapes fixed by the reference)
#define DIM 1024
#define NH 16
#define HD 64
#define S_ORIG 8704
#define WIN 512          // L * WINDOW = 256*2

typedef __attribute__((ext_vector_type(8))) short short8;
typedef __attribute__((ext_vector_type(4))) float f32x4;

__device__ __forceinline__ float bf2f(unsigned short u) {
    return __uint_as_float(((unsigned int)u) << 16);
}
__device__ __forceinline__ unsigned short f2bf(float f) {
    unsigned int x = __float_as_uint(f);
    unsigned int r = x + 0x7fffu + ((x >> 16) & 1u);   // RNE
    return (unsigned short)(r >> 16);
}
// pack two fp32 -> bf16x2 (round-half-up; inputs are finite non-negative exp values)
__device__ __forceinline__ unsigned int pkbf(float a, float b) {
    unsigned int ua = (__float_as_uint(a) + 0x8000u) >> 16;
    unsigned int ub = (__float_as_uint(b) + 0x8000u) & 0xffff0000u;
    return ua | ub;
}

// ---------------- merged prep: fp32->bf16 convert (x) + weight transpose ----------------
// blocks [0, 8704): cvt; blocks [8704, 9728): transpose (one launch, one less bubble)
__global__ __launch_bounds__(256) void prep(const float* __restrict__ x,
                                            unsigned short* __restrict__ xb,
                                            const float* __restrict__ w0,
                                            const float* __restrict__ w1,
                                            const float* __restrict__ w2,
                                            const float* __restrict__ w3,
                                            unsigned short* __restrict__ wt) {
    __shared__ float ts[64][65];
    const int bx = blockIdx.x;
    const int t = threadIdx.x;
    if (bx < 8704) {
        int i = (bx * 256 + t) * 4;   // total = 8704*1024, exact
        float4 v = *(const float4*)(x + i);
        ushort4 o;
        o.x = f2bf(v.x); o.y = f2bf(v.y); o.z = f2bf(v.z); o.w = f2bf(v.w);
        *(ushort4*)(xb + i) = o;
        return;
    }
    const int b = bx - 8704;
    const int z = b >> 8;
    const int rem = b & 255;
    const int kb = (rem >> 4) * 64, nb = (rem & 15) * 64;
    const float* w = z == 0 ? w0 : z == 1 ? w1 : z == 2 ? w2 : w3;
    unsigned short* o = wt + (size_t)z * DIM * DIM;
    const int c = t & 63, r4 = t >> 6;
#pragma unroll
    for (int rr = 0; rr < 16; rr++) {
        int row = rr * 4 + r4;
        ts[row][c] = w[(size_t)(kb + row) * DIM + nb + c];
    }
    __syncthreads();
#pragma unroll
    for (int rr = 0; rr < 16; rr++) {
        int nl = rr * 4 + r4;
        o[(size_t)(nb + nl) * DIM + kb + c] = f2bf(ts[c][nl]);
    }
}

// ---------------- bf16 MFMA GEMM: C[M,N] = A[M,K] * Bt[N,K]^T + bias ----------------
// 128x128 tile, 4 waves, BK=32. Round-1 register-prefetch staging (measured ~65us
// faster than global_load_lds here: loads issue BEFORE barrier 1, overlapping their
// latency with the previous iteration's MFMA drain + barrier wait; GLD_LDS serializes
// DMA between the two barriers behind a vmcnt(0) drain). XOR bank swizzle on the LDS
// chunk placement keeps frag reads at the free 2-way conflict level.
template <int OUTF32>
__global__ __launch_bounds__(256) void gemm_bf16(const unsigned short* __restrict__ A,
                                                 const unsigned short* __restrict__ Bt,
                                                 const float* __restrict__ b0,
                                                 const float* __restrict__ b1,
                                                 const float* __restrict__ b2,
                                                 void* __restrict__ Cout) {
    __shared__ __align__(16) unsigned short As[128 * 32];
    __shared__ __align__(16) unsigned short Bs[128 * 32];
    const int z = blockIdx.z;
    const unsigned short* B = Bt + (size_t)z * DIM * DIM;
    const float* bias = z == 0 ? b0 : (z == 1 ? b1 : b2);
    const int m0 = blockIdx.y * 128, n0 = blockIdx.x * 128;
    const int tid = threadIdx.x;
    const int lane = tid & 63, wv = tid >> 6;
    const int wr = wv >> 1, wc = wv & 1;
    const int quad = lane >> 4, r = lane & 15;

    f32x4 acc[4][4];
#pragma unroll
    for (int i = 0; i < 4; i++)
#pragma unroll
        for (int j = 0; j < 4; j++)
#pragma unroll
            for (int t4 = 0; t4 < 4; t4++) acc[i][j][t4] = 0.0f;

    const unsigned short* a_base = A + (size_t)m0 * DIM;
    const unsigned short* b_base = B + (size_t)n0 * DIM;
    // staging chunk c (16B): row = c>>2, physical slot c&3; holds global col-chunk
    // gc = (c&3) ^ ((c>>3)&3)  (XOR swizzle; (c>>3)&3 == (row>>1)&3)
    const int c0 = tid, c1 = 256 + tid;
    const int r0 = c0 >> 2, o0 = (((c0 & 3) ^ ((c0 >> 3) & 3))) * 8;
    const int r1 = c1 >> 2, o1 = (((c1 & 3) ^ ((c1 >> 3) & 3))) * 8;
    // frag-read physical chunk: quad ^ ((row>>1)&3) == quad ^ ((r>>1)&3) (base mult of 16)
    const int jsw = (quad ^ ((r >> 1) & 3)) * 8;

    for (int k0 = 0; k0 < DIM; k0 += 32) {
        int4 a0 = *(const int4*)(a_base + (size_t)r0 * DIM + k0 + o0);
        int4 a1 = *(const int4*)(a_base + (size_t)r1 * DIM + k0 + o1);
        int4 g0 = *(const int4*)(b_base + (size_t)r0 * DIM + k0 + o0);
        int4 g1 = *(const int4*)(b_base + (size_t)r1 * DIM + k0 + o1);
        __syncthreads();   // previous iteration's frag readers done before overwrite
        *(int4*)&As[c0 * 8] = a0;
        *(int4*)&As[c1 * 8] = a1;
        *(int4*)&Bs[c0 * 8] = g0;
        *(int4*)&Bs[c1 * 8] = g1;
        __syncthreads();
        short8 af[4], bfr[4];
#pragma unroll
        for (int i = 0; i < 4; i++)
            af[i] = *(const short8*)&As[(wr * 64 + i * 16 + r) * 32 + jsw];
#pragma unroll
        for (int j = 0; j < 4; j++)
            bfr[j] = *(const short8*)&Bs[(wc * 64 + j * 16 + r) * 32 + jsw];
#pragma unroll
        for (int i = 0; i < 4; i++)
#pragma unroll
            for (int j = 0; j < 4; j++)
                acc[i][j] = __builtin_amdgcn_mfma_f32_16x16x32_bf16(af[i], bfr[j], acc[i][j], 0, 0, 0);
    }

    // epilogue: C/D layout col = lane&15, row = quad*4 + reg
#pragma unroll
    for (int i = 0; i < 4; i++) {
        const int row = m0 + wr * 64 + i * 16 + quad * 4;
#pragma unroll
        for (int j = 0; j < 4; j++) {
            const int col = n0 + wc * 64 + j * 16 + r;
            const float bvl = bias[col];
#pragma unroll
            for (int t4 = 0; t4 < 4; t4++) {
                float vv = acc[i][j][t4] + bvl;
                if (OUTF32) {
                    ((float*)Cout)[(size_t)(row + t4) * DIM + col] = vv;
                } else {
                    ((unsigned short*)Cout)[(size_t)z * S_ORIG * DIM + (size_t)(row + t4) * DIM + col] = f2bf(vv);
                }
            }
        }
    }
}

// ---------------- fused RMSNorm + RoPE, wave-per-row (no LDS, no barrier) ----------------
// grid (2176, 2), 4 waves/block, wave w owns row blockIdx.x*4 + w. Lane holds 16 elems
// (8 at lane*8, 8 at 512+lane*8; same in-head offset since 512 % 64 == 0 -> shared cos/sin).
__global__ __launch_bounds__(256) void norm_rope(unsigned short* __restrict__ hq,
                                                 unsigned short* __restrict__ hk,
                                                 const float* __restrict__ gq,
                                                 const float* __restrict__ gk,
                                                 const float* __restrict__ fcos,
                                                 const float* __restrict__ fsin) {
    const int z = blockIdx.y;
    unsigned short* h = z == 0 ? hq : hk;
    const float* g = z == 0 ? gq : gk;
    const int w = threadIdx.x >> 6, lane = threadIdx.x & 63;
    const int srow = blockIdx.x * 4 + w;
    unsigned short* hp = h + (size_t)srow * DIM;
    const int p0 = lane * 8, p1 = 512 + lane * 8;

    union { int4 i4; unsigned short u[8]; } r0, r1, o0, o1;
    r0.i4 = *(const int4*)(hp + p0);
    r1.i4 = *(const int4*)(hp + p1);
    float v[16];
#pragma unroll
    for (int j = 0; j < 8; j++) { v[j] = bf2f(r0.u[j]); v[8 + j] = bf2f(r1.u[j]); }

    float ss = 0.0f;
#pragma unroll
    for (int j = 0; j < 16; j++) ss += v[j] * v[j];
#pragma unroll
    for (int off = 1; off < 64; off <<= 1) ss += __shfl_xor(ss, off, 64);
    const float rinv = rsqrtf(ss * (1.0f / DIM) + 1e-6f);

    float4 ga = *(const float4*)(g + p0), gb = *(const float4*)(g + p0 + 4);
    float4 gc = *(const float4*)(g + p1), gd = *(const float4*)(g + p1 + 4);
    const float* gg[4] = {&ga.x, &gb.x, &gc.x, &gd.x};
#pragma unroll
    for (int q4 = 0; q4 < 4; q4++)
#pragma unroll
        for (int j = 0; j < 4; j++) v[q4 * 4 + j] *= rinv * gg[q4][j];

    const int i0 = (p0 & 63) >> 1;   // pair base within head (mult of 4); same for p1
    float4 cs = *(const float4*)(fcos + (size_t)srow * 32 + i0);
    float4 sn = *(const float4*)(fsin + (size_t)srow * 32 + i0);
    const float* cp = &cs.x;
    const float* sp = &sn.x;
#pragma unroll
    for (int seg = 0; seg < 2; seg++) {
        unsigned short* uo = seg == 0 ? o0.u : o1.u;
#pragma unroll
        for (int pr = 0; pr < 4; pr++) {
            const float a = v[seg * 8 + pr * 2], b = v[seg * 8 + pr * 2 + 1];
            uo[pr * 2]     = f2bf(a * cp[pr] - b * sp[pr]);
            uo[pr * 2 + 1] = f2bf(a * sp[pr] + b * cp[pr]);
        }
    }
    *(int4*)(hp + p0) = o0.i4;
    *(int4*)(hp + p1) = o1.i4;
}

// ---------------- dilated sliding-window attention, transposed-MFMA flash ----------------
// Round-5 version verbatim (proven 92.8us; round-6's exp2f lowered to the slow OCML
// path, +9us / VALUBusy +11pts). grid: (32 = head*2+stream, 68 qtiles). S^T = K*Q^T
// (col = q = lane&15): per-lane softmax, no in-loop cross-lane reductions; fixed-max
// softmax (scores bounded); l reduced once at the end via 2 shuffles.
// Zero-pad key tiles (kt>=68) contribute l += count analytically (exp(0)=1, V=0).
__global__ __launch_bounds__(256) void attn(const unsigned short* __restrict__ qkv,
                                            unsigned short* __restrict__ ob) {
    __shared__ __align__(16) unsigned short Ks[64 * 72];
    __shared__ __align__(16) unsigned short Vt[64 * 72];
    __shared__ __align__(16) unsigned short Ps[4][16 * 72];

    const int head = blockIdx.x >> 1;
    const int d = blockIdx.x & 1;
    const int qt = blockIdx.y;
    const int tid = threadIdx.x;
    const int lane = tid & 63, wv = tid >> 6;
    const int quad = lane >> 4, r16 = lane & 15;

    const unsigned short* qb = qkv;
    const unsigned short* kb = qkv + (size_t)S_ORIG * DIM;
    const unsigned short* vb = qkv + (size_t)2 * S_ORIG * DIM;

    // --- this lane's query (B-operand of S^T): q = r16 within wave tile ---
    const int qi = qt * 64 + wv * 16 + r16;
    const int og_q = ((qi >> 8) << 9) + d * 256 + (qi & 255);
    short8 qf[2];
    {
        const unsigned short* qrow = qb + (size_t)og_q * DIM + head * HD + quad * 8;
#pragma unroll
        for (int c = 0; c < 2; c++) {
            union { int4 i4; unsigned short u[8]; short8 s8; } in, outv;
            in.i4 = *(const int4*)(qrow + c * 32);
#pragma unroll
            for (int j = 0; j < 8; j++) outv.u[j] = f2bf(bf2f(in.u[j]) * 0.125f);
            qf[c] = outv.s8;
        }
    }

    f32x4 oacc[4];     // O^T: row d_local = quad*4+reg (tile nt), col q = r16
    float lsum = 0.0f;
#pragma unroll
    for (int nt = 0; nt < 4; nt++)
#pragma unroll
        for (int rr = 0; rr < 4; rr++) oacc[nt][rr] = 0.0f;

    // real-key tiles only; kt>=68 are all-zero pad rows handled analytically below
    const int kt_lo = (qt - 8 > 0) ? (qt - 8) : 0;
    const int kt_hi = (qt + 8 < 67) ? (qt + 8) : 67;

    // per-thread staging coords (hoisted)
    const int st_row0 = tid >> 3, st_ch = (tid & 7) * 8;          // K: rows tid>>3, +32
    const int vt_kk = (tid & 31) * 2, vt_d0 = (tid >> 5) * 8;     // V^T

    for (int kt = kt_lo; kt <= kt_hi; kt++) {
        const int kbase = kt * 64;
        __syncthreads();   // previous tile's frag readers done before overwrite

        // stage K [kk][d], rows padded to 72 bf16 (kt<=67 => always in-bounds)
#pragma unroll
        for (int half = 0; half < 2; half++) {
            const int row = st_row0 + half * 32;
            const int kj = kbase + row;
            const int ok = ((kj >> 8) << 9) + d * 256 + (kj & 255);
            *(int4*)&Ks[row * 72 + st_ch] = *(const int4*)(kb + (size_t)ok * DIM + head * HD + st_ch);
        }
        // stage V transposed: Vt[d][kk]
        {
            const int kj0 = kbase + vt_kk;
            const int ok0 = ((kj0 >> 8) << 9) + d * 256 + (kj0 & 255);
            union { int4 i4; unsigned short u[8]; } a0, a1;
            a0.i4 = *(const int4*)(vb + (size_t)ok0 * DIM + head * HD + vt_d0);
            a1.i4 = *(const int4*)(vb + (size_t)(ok0 + 1) * DIM + head * HD + vt_d0);
#pragma unroll
            for (int i = 0; i < 8; i++) {
                unsigned int pack = (unsigned int)a0.u[i] | ((unsigned int)a1.u[i] << 16);
                *(unsigned int*)&Vt[(vt_d0 + i) * 72 + vt_kk] = pack;
            }
        }
        __syncthreads();

        // --- S^T[kk][q]: A-op = K rows, B-op = Q frag ---
        f32x4 sv[4];
#pragma unroll
        for (int nt = 0; nt < 4; nt++) {
            short8 k0f = *(const short8*)&Ks[(nt * 16 + r16) * 72 + quad * 8];
            short8 k1f = *(const short8*)&Ks[(nt * 16 + r16) * 72 + 32 + quad * 8];
            f32x4 a = {0.0f, 0.0f, 0.0f, 0.0f};
            a = __builtin_amdgcn_mfma_f32_16x16x32_bf16(k0f, qf[0], a, 0, 0, 0);
            a = __builtin_amdgcn_mfma_f32_16x16x32_bf16(k1f, qf[1], a, 0, 0, 0);
            sv[nt] = a;
        }

        // --- exp (no max subtraction: scores bounded), window mask on edge tiles only ---
        const bool edge = (kt == qt - 8) || (kt == qt + 8);
        unsigned short* pw = &Ps[wv][0];
#pragma unroll
        for (int nt = 0; nt < 4; nt++) {
            float p[4];
#pragma unroll
            for (int rr = 0; rr < 4; rr++) {
                float e = __expf(sv[nt][rr]);
                if (edge) {
                    const int kj = kbase + nt * 16 + quad * 4 + rr;
                    const int dl = qi - kj;
                    if (dl > WIN || dl < -WIN) e = 0.0f;
                }
                p[rr] = e;
            }
            lsum += (p[0] + p[1]) + (p[2] + p[3]);
            uint2 pk;
            pk.x = pkbf(p[0], p[1]);
            pk.y = pkbf(p[2], p[3]);
            *(uint2*)&pw[r16 * 72 + nt * 16 + quad * 4] = pk;
        }
        __asm__ volatile("s_waitcnt lgkmcnt(0)" ::: "memory");

        // --- O^T += V^T * P^T : A-op = Vt rows, B-op = P frag (A-layout of P) ---
        short8 pf0 = *(const short8*)&pw[r16 * 72 + quad * 8];
        short8 pf1 = *(const short8*)&pw[r16 * 72 + 32 + quad * 8];
#pragma unroll
        for (int nt = 0; nt < 4; nt++) {
            short8 v0f = *(const short8*)&Vt[(nt * 16 + r16) * 72 + quad * 8];
            short8 v1f = *(const short8*)&Vt[(nt * 16 + r16) * 72 + 32 + quad * 8];
            oacc[nt] = __builtin_amdgcn_mfma_f32_16x16x32_bf16(v0f, pf0, oacc[nt], 0, 0, 0);
            oacc[nt] = __builtin_amdgcn_mfma_f32_16x16x32_bf16(v1f, pf1, oacc[nt], 0, 0, 0);
        }
    }

    // --- final l: reduce across the 4 quads (other lanes hold other kk of same q) ---
    lsum += __shfl_xor(lsum, 16, 64);
    lsum += __shfl_xor(lsum, 32, 64);
    // zero-pad keys (dilated pos >= 4352 -> orig >= 8704, K=V=0): score 0 -> exp=1 each
    {
        const int cnt = (qi + WIN < 4607 ? qi + WIN : 4607) - 4351;
        if (cnt > 0) lsum += (float)cnt;
    }
    const float linv = 1.0f / lsum;

    // --- write O: lane owns q = r16; 4 consecutive dims per nt ---
#pragma unroll
    for (int nt = 0; nt < 4; nt++) {
        ushort4 o;
        o.x = f2bf(oacc[nt][0] * linv);
        o.y = f2bf(oacc[nt][1] * linv);
        o.z = f2bf(oacc[nt][2] * linv);
        o.w = f2bf(oacc[nt][3] * linv);
        *(ushort4*)&ob[(size_t)og_q * DIM + head * HD + nt * 16 + quad * 4] = o;
    }
}

// ---------------- launch ----------------
extern "C" void kernel_launch(void* const* d_in, const int* in_sizes, int n_in,
                              void* d_out, int out_size, void* d_ws, size_t ws_size,
                              hipStream_t stream) {
    const float* x    = (const float*)d_in[0];
    const float* fcos = (const float*)d_in[1];
    const float* fsin = (const float*)d_in[2];
    const float* wq   = (const float*)d_in[3];
    const float* bq   = (const float*)d_in[4];
    const float* wk   = (const float*)d_in[5];
    const float* bk   = (const float*)d_in[6];
    const float* wv   = (const float*)d_in[7];
    const float* bv   = (const float*)d_in[8];
    const float* wo   = (const float*)d_in[9];
    const float* bo   = (const float*)d_in[10];
    const float* gq   = (const float*)d_in[11];
    const float* gk   = (const float*)d_in[12];

    char* ws = (char*)d_ws;
    unsigned short* xb = (unsigned short*)(ws);
    unsigned short* wt = (unsigned short*)(ws + 17825792);
    unsigned short* h  = (unsigned short*)(ws + 26214400);
    unsigned short* ob = (unsigned short*)(ws + 79691776);
    float* outp = (float*)d_out;

    prep<<<9728, 256, 0, stream>>>(x, xb, wq, wk, wv, wo, wt);
    gemm_bf16<0><<<dim3(8, 68, 3), 256, 0, stream>>>(xb, wt, bq, bk, bv, (void*)h);
    norm_rope<<<dim3(2176, 2), 256, 0, stream>>>(h, h + (size_t)S_ORIG * DIM, gq, gk, fcos, fsin);
    attn<<<dim3(32, 68), 256, 0, stream>>>(h, ob);
    gemm_bf16<1><<<dim3(8, 68, 1), 256, 0, stream>>>(ob, wt + (size_t)3 * DIM * DIM, bo, bo, bo, (void*)outp);
}

// Round 8
// 317.380 us; speedup vs baseline: 1.1097x; 1.1097x over previous
//
#include <hip/hip_runtime.h>
#include <hip/hip_bf16.h>
#include <stdint.h>

// Problem constants (shapes fixed by the reference)
#define DIM 1024
#define NH 16
#define HD 64
#define S_ORIG 8704
#define WIN 512          // L * WINDOW = 256*2

typedef __attribute__((ext_vector_type(8))) short short8;
typedef __attribute__((ext_vector_type(4))) float f32x4;

__device__ __forceinline__ float bf2f(unsigned short u) {
    return __uint_as_float(((unsigned int)u) << 16);
}
__device__ __forceinline__ unsigned short f2bf(float f) {
    unsigned int x = __float_as_uint(f);
    unsigned int r = x + 0x7fffu + ((x >> 16) & 1u);   // RNE
    return (unsigned short)(r >> 16);
}
// pack two fp32 -> bf16x2 (round-half-up; inputs are finite non-negative exp values)
__device__ __forceinline__ unsigned int pkbf(float a, float b) {
    unsigned int ua = (__float_as_uint(a) + 0x8000u) >> 16;
    unsigned int ub = (__float_as_uint(b) + 0x8000u) & 0xffff0000u;
    return ua | ub;
}

#define GLD_LDS(gptr, lptr) \
    __builtin_amdgcn_global_load_lds((const __attribute__((address_space(1))) void*)(gptr), \
                                     (__attribute__((address_space(3))) void*)(lptr), 16, 0, 0)

// ---------------- merged prep: fp32->bf16 convert (x) + weight transpose ----------------
// blocks [0, 8704): cvt; blocks [8704, 9728): transpose (one launch, one less bubble)
__global__ __launch_bounds__(256) void prep(const float* __restrict__ x,
                                            unsigned short* __restrict__ xb,
                                            const float* __restrict__ w0,
                                            const float* __restrict__ w1,
                                            const float* __restrict__ w2,
                                            const float* __restrict__ w3,
                                            unsigned short* __restrict__ wt) {
    __shared__ float ts[64][65];
    const int bx = blockIdx.x;
    const int t = threadIdx.x;
    if (bx < 8704) {
        int i = (bx * 256 + t) * 4;   // total = 8704*1024, exact
        float4 v = *(const float4*)(x + i);
        ushort4 o;
        o.x = f2bf(v.x); o.y = f2bf(v.y); o.z = f2bf(v.z); o.w = f2bf(v.w);
        *(ushort4*)(xb + i) = o;
        return;
    }
    const int b = bx - 8704;
    const int z = b >> 8;
    const int rem = b & 255;
    const int kb = (rem >> 4) * 64, nb = (rem & 15) * 64;
    const float* w = z == 0 ? w0 : z == 1 ? w1 : z == 2 ? w2 : w3;
    unsigned short* o = wt + (size_t)z * DIM * DIM;
    const int c = t & 63, r4 = t >> 6;
#pragma unroll
    for (int rr = 0; rr < 16; rr++) {
        int row = rr * 4 + r4;
        ts[row][c] = w[(size_t)(kb + row) * DIM + nb + c];
    }
    __syncthreads();
#pragma unroll
    for (int rr = 0; rr < 16; rr++) {
        int nl = rr * 4 + r4;
        o[(size_t)(nb + nl) * DIM + kb + c] = f2bf(ts[c][nl]);
    }
}

// ---------------- bf16 MFMA GEMM: C[M,N] = A[M,K] * Bt[N,K]^T + bias ----------------
// 128x128 tile, 4 waves, BK=32, global_load_lds width-16 staging (round-5 variant,
// measured faster than register-prefetch: <=92.5 vs 115us) + XOR bank swizzle.
// Grid is (m=68, n=8, z): consecutive linear blocks vary over m, so an A strip is
// touched by only 2 distinct XCDs ((m+4n)%8) instead of 8 -> A re-fetch 8x -> 2x
// (R7 measured FETCH=215MB vs 24MB unique with the n-fastest ordering).
template <int OUTF32>
__global__ __launch_bounds__(256) void gemm_bf16(const unsigned short* __restrict__ A,
                                                 const unsigned short* __restrict__ Bt,
                                                 const float* __restrict__ b0,
                                                 const float* __restrict__ b1,
                                                 const float* __restrict__ b2,
                                                 void* __restrict__ Cout) {
    __shared__ __align__(16) unsigned short As[128 * 32];
    __shared__ __align__(16) unsigned short Bs[128 * 32];
    const int z = blockIdx.z;
    const unsigned short* B = Bt + (size_t)z * DIM * DIM;
    const float* bias = z == 0 ? b0 : (z == 1 ? b1 : b2);
    const int m0 = blockIdx.x * 128, n0 = blockIdx.y * 128;   // m fastest (XCD locality)
    const int tid = threadIdx.x;
    const int lane = tid & 63, wv = tid >> 6;
    const int wr = wv >> 1, wc = wv & 1;
    const int quad = lane >> 4, r = lane & 15;

    f32x4 acc[4][4];
#pragma unroll
    for (int i = 0; i < 4; i++)
#pragma unroll
        for (int j = 0; j < 4; j++)
#pragma unroll
            for (int t4 = 0; t4 < 4; t4++) acc[i][j][t4] = 0.0f;

    const unsigned short* a_base = A + (size_t)m0 * DIM;
    const unsigned short* b_base = B + (size_t)n0 * DIM;
    // staging chunk c (16B): row = c>>2, physical slot c&3; holds global col-chunk
    // gc = (c&3) ^ ((c>>3)&3). Per-wave GLD instr i covers slots wv*128 + i*64 + lane.
    const int c0 = wv * 128 + lane;
    const int r0 = c0 >> 2, o0 = (((c0 & 3) ^ ((c0 >> 3) & 3))) * 8;
    const int c1 = c0 + 64;
    const int r1 = c1 >> 2, o1 = (((c1 & 3) ^ ((c1 >> 3) & 3))) * 8;
    unsigned short* lA0 = &As[(size_t)(wv * 128) * 8];
    unsigned short* lA1 = &As[(size_t)(wv * 128 + 64) * 8];
    unsigned short* lB0 = &Bs[(size_t)(wv * 128) * 8];
    unsigned short* lB1 = &Bs[(size_t)(wv * 128 + 64) * 8];

    // frag-read physical chunk: quad ^ ((row>>1)&3) == quad ^ ((r>>1)&3) (base mult of 16)
    const int jsw = (quad ^ ((r >> 1) & 3)) * 8;

    for (int k0 = 0; k0 < DIM; k0 += 32) {
        __syncthreads();   // previous iteration's frag readers done before DMA overwrites
        GLD_LDS(a_base + (size_t)r0 * DIM + k0 + o0, lA0);
        GLD_LDS(a_base + (size_t)r1 * DIM + k0 + o1, lA1);
        GLD_LDS(b_base + (size_t)r0 * DIM + k0 + o0, lB0);
        GLD_LDS(b_base + (size_t)r1 * DIM + k0 + o1, lB1);
        __syncthreads();   // vmcnt(0) drain
        short8 af[4], bfr[4];
#pragma unroll
        for (int i = 0; i < 4; i++)
            af[i] = *(const short8*)&As[(wr * 64 + i * 16 + r) * 32 + jsw];
#pragma unroll
        for (int j = 0; j < 4; j++)
            bfr[j] = *(const short8*)&Bs[(wc * 64 + j * 16 + r) * 32 + jsw];
#pragma unroll
        for (int i = 0; i < 4; i++)
#pragma unroll
            for (int j = 0; j < 4; j++)
                acc[i][j] = __builtin_amdgcn_mfma_f32_16x16x32_bf16(af[i], bfr[j], acc[i][j], 0, 0, 0);
    }

    // epilogue: C/D layout col = lane&15, row = quad*4 + reg
#pragma unroll
    for (int i = 0; i < 4; i++) {
        const int row = m0 + wr * 64 + i * 16 + quad * 4;
#pragma unroll
        for (int j = 0; j < 4; j++) {
            const int col = n0 + wc * 64 + j * 16 + r;
            const float bvl = bias[col];
#pragma unroll
            for (int t4 = 0; t4 < 4; t4++) {
                float vv = acc[i][j][t4] + bvl;
                if (OUTF32) {
                    ((float*)Cout)[(size_t)(row + t4) * DIM + col] = vv;
                } else {
                    ((unsigned short*)Cout)[(size_t)z * S_ORIG * DIM + (size_t)(row + t4) * DIM + col] = f2bf(vv);
                }
            }
        }
    }
}

// ---------------- fused RMSNorm + RoPE, wave-per-row (no LDS, no barrier) ----------------
// grid (2176, 2), 4 waves/block, wave w owns row blockIdx.x*4 + w. Lane holds 16 elems
// (8 at lane*8, 8 at 512+lane*8; same in-head offset since 512 % 64 == 0 -> shared cos/sin).
__global__ __launch_bounds__(256) void norm_rope(unsigned short* __restrict__ hq,
                                                 unsigned short* __restrict__ hk,
                                                 const float* __restrict__ gq,
                                                 const float* __restrict__ gk,
                                                 const float* __restrict__ fcos,
                                                 const float* __restrict__ fsin) {
    const int z = blockIdx.y;
    unsigned short* h = z == 0 ? hq : hk;
    const float* g = z == 0 ? gq : gk;
    const int w = threadIdx.x >> 6, lane = threadIdx.x & 63;
    const int srow = blockIdx.x * 4 + w;
    unsigned short* hp = h + (size_t)srow * DIM;
    const int p0 = lane * 8, p1 = 512 + lane * 8;

    union { int4 i4; unsigned short u[8]; } r0, r1, o0, o1;
    r0.i4 = *(const int4*)(hp + p0);
    r1.i4 = *(const int4*)(hp + p1);
    float v[16];
#pragma unroll
    for (int j = 0; j < 8; j++) { v[j] = bf2f(r0.u[j]); v[8 + j] = bf2f(r1.u[j]); }

    float ss = 0.0f;
#pragma unroll
    for (int j = 0; j < 16; j++) ss += v[j] * v[j];
#pragma unroll
    for (int off = 1; off < 64; off <<= 1) ss += __shfl_xor(ss, off, 64);
    const float rinv = rsqrtf(ss * (1.0f / DIM) + 1e-6f);

    float4 ga = *(const float4*)(g + p0), gb = *(const float4*)(g + p0 + 4);
    float4 gc = *(const float4*)(g + p1), gd = *(const float4*)(g + p1 + 4);
    const float* gg[4] = {&ga.x, &gb.x, &gc.x, &gd.x};
#pragma unroll
    for (int q4 = 0; q4 < 4; q4++)
#pragma unroll
        for (int j = 0; j < 4; j++) v[q4 * 4 + j] *= rinv * gg[q4][j];

    const int i0 = (p0 & 63) >> 1;   // pair base within head (mult of 4); same for p1
    float4 cs = *(const float4*)(fcos + (size_t)srow * 32 + i0);
    float4 sn = *(const float4*)(fsin + (size_t)srow * 32 + i0);
    const float* cp = &cs.x;
    const float* sp = &sn.x;
#pragma unroll
    for (int seg = 0; seg < 2; seg++) {
        unsigned short* uo = seg == 0 ? o0.u : o1.u;
#pragma unroll
        for (int pr = 0; pr < 4; pr++) {
            const float a = v[seg * 8 + pr * 2], b = v[seg * 8 + pr * 2 + 1];
            uo[pr * 2]     = f2bf(a * cp[pr] - b * sp[pr]);
            uo[pr * 2 + 1] = f2bf(a * sp[pr] + b * cp[pr]);
        }
    }
    *(int4*)(hp + p0) = o0.i4;
    *(int4*)(hp + p1) = o1.i4;
}

// ---------------- dilated sliding-window attention, transposed-MFMA flash ----------------
// Round-5 version verbatim (proven 92.8us). grid: (32 = head*2+stream, 68 qtiles).
// S^T = K*Q^T (col = q = lane&15): per-lane softmax, no in-loop cross-lane reductions;
// fixed-max softmax (scores bounded); l reduced once at the end via 2 shuffles.
// Zero-pad key tiles (kt>=68) contribute l += count analytically (exp(0)=1, V=0).
__global__ __launch_bounds__(256) void attn(const unsigned short* __restrict__ qkv,
                                            unsigned short* __restrict__ ob) {
    __shared__ __align__(16) unsigned short Ks[64 * 72];
    __shared__ __align__(16) unsigned short Vt[64 * 72];
    __shared__ __align__(16) unsigned short Ps[4][16 * 72];

    const int head = blockIdx.x >> 1;
    const int d = blockIdx.x & 1;
    const int qt = blockIdx.y;
    const int tid = threadIdx.x;
    const int lane = tid & 63, wv = tid >> 6;
    const int quad = lane >> 4, r16 = lane & 15;

    const unsigned short* qb = qkv;
    const unsigned short* kb = qkv + (size_t)S_ORIG * DIM;
    const unsigned short* vb = qkv + (size_t)2 * S_ORIG * DIM;

    // --- this lane's query (B-operand of S^T): q = r16 within wave tile ---
    const int qi = qt * 64 + wv * 16 + r16;
    const int og_q = ((qi >> 8) << 9) + d * 256 + (qi & 255);
    short8 qf[2];
    {
        const unsigned short* qrow = qb + (size_t)og_q * DIM + head * HD + quad * 8;
#pragma unroll
        for (int c = 0; c < 2; c++) {
            union { int4 i4; unsigned short u[8]; short8 s8; } in, outv;
            in.i4 = *(const int4*)(qrow + c * 32);
#pragma unroll
            for (int j = 0; j < 8; j++) outv.u[j] = f2bf(bf2f(in.u[j]) * 0.125f);
            qf[c] = outv.s8;
        }
    }

    f32x4 oacc[4];     // O^T: row d_local = quad*4+reg (tile nt), col q = r16
    float lsum = 0.0f;
#pragma unroll
    for (int nt = 0; nt < 4; nt++)
#pragma unroll
        for (int rr = 0; rr < 4; rr++) oacc[nt][rr] = 0.0f;

    // real-key tiles only; kt>=68 are all-zero pad rows handled analytically below
    const int kt_lo = (qt - 8 > 0) ? (qt - 8) : 0;
    const int kt_hi = (qt + 8 < 67) ? (qt + 8) : 67;

    // per-thread staging coords (hoisted)
    const int st_row0 = tid >> 3, st_ch = (tid & 7) * 8;          // K: rows tid>>3, +32
    const int vt_kk = (tid & 31) * 2, vt_d0 = (tid >> 5) * 8;     // V^T

    for (int kt = kt_lo; kt <= kt_hi; kt++) {
        const int kbase = kt * 64;
        __syncthreads();   // previous tile's frag readers done before overwrite

        // stage K [kk][d], rows padded to 72 bf16 (kt<=67 => always in-bounds)
#pragma unroll
        for (int half = 0; half < 2; half++) {
            const int row = st_row0 + half * 32;
            const int kj = kbase + row;
            const int ok = ((kj >> 8) << 9) + d * 256 + (kj & 255);
            *(int4*)&Ks[row * 72 + st_ch] = *(const int4*)(kb + (size_t)ok * DIM + head * HD + st_ch);
        }
        // stage V transposed: Vt[d][kk]
        {
            const int kj0 = kbase + vt_kk;
            const int ok0 = ((kj0 >> 8) << 9) + d * 256 + (kj0 & 255);
            union { int4 i4; unsigned short u[8]; } a0, a1;
            a0.i4 = *(const int4*)(vb + (size_t)ok0 * DIM + head * HD + vt_d0);
            a1.i4 = *(const int4*)(vb + (size_t)(ok0 + 1) * DIM + head * HD + vt_d0);
#pragma unroll
            for (int i = 0; i < 8; i++) {
                unsigned int pack = (unsigned int)a0.u[i] | ((unsigned int)a1.u[i] << 16);
                *(unsigned int*)&Vt[(vt_d0 + i) * 72 + vt_kk] = pack;
            }
        }
        __syncthreads();

        // --- S^T[kk][q]: A-op = K rows, B-op = Q frag ---
        f32x4 sv[4];
#pragma unroll
        for (int nt = 0; nt < 4; nt++) {
            short8 k0f = *(const short8*)&Ks[(nt * 16 + r16) * 72 + quad * 8];
            short8 k1f = *(const short8*)&Ks[(nt * 16 + r16) * 72 + 32 + quad * 8];
            f32x4 a = {0.0f, 0.0f, 0.0f, 0.0f};
            a = __builtin_amdgcn_mfma_f32_16x16x32_bf16(k0f, qf[0], a, 0, 0, 0);
            a = __builtin_amdgcn_mfma_f32_16x16x32_bf16(k1f, qf[1], a, 0, 0, 0);
            sv[nt] = a;
        }

        // --- exp (no max subtraction: scores bounded), window mask on edge tiles only ---
        const bool edge = (kt == qt - 8) || (kt == qt + 8);
        unsigned short* pw = &Ps[wv][0];
#pragma unroll
        for (int nt = 0; nt < 4; nt++) {
            float p[4];
#pragma unroll
            for (int rr = 0; rr < 4; rr++) {
                float e = __expf(sv[nt][rr]);
                if (edge) {
                    const int kj = kbase + nt * 16 + quad * 4 + rr;
                    const int dl = qi - kj;
                    if (dl > WIN || dl < -WIN) e = 0.0f;
                }
                p[rr] = e;
            }
            lsum += (p[0] + p[1]) + (p[2] + p[3]);
            uint2 pk;
            pk.x = pkbf(p[0], p[1]);
            pk.y = pkbf(p[2], p[3]);
            *(uint2*)&pw[r16 * 72 + nt * 16 + quad * 4] = pk;
        }
        __asm__ volatile("s_waitcnt lgkmcnt(0)" ::: "memory");

        // --- O^T += V^T * P^T : A-op = Vt rows, B-op = P frag (A-layout of P) ---
        short8 pf0 = *(const short8*)&pw[r16 * 72 + quad * 8];
        short8 pf1 = *(const short8*)&pw[r16 * 72 + 32 + quad * 8];
#pragma unroll
        for (int nt = 0; nt < 4; nt++) {
            short8 v0f = *(const short8*)&Vt[(nt * 16 + r16) * 72 + quad * 8];
            short8 v1f = *(const short8*)&Vt[(nt * 16 + r16) * 72 + 32 + quad * 8];
            oacc[nt] = __builtin_amdgcn_mfma_f32_16x16x32_bf16(v0f, pf0, oacc[nt], 0, 0, 0);
            oacc[nt] = __builtin_amdgcn_mfma_f32_16x16x32_bf16(v1f, pf1, oacc[nt], 0, 0, 0);
        }
    }

    // --- final l: reduce across the 4 quads (other lanes hold other kk of same q) ---
    lsum += __shfl_xor(lsum, 16, 64);
    lsum += __shfl_xor(lsum, 32, 64);
    // zero-pad keys (dilated pos >= 4352 -> orig >= 8704, K=V=0): score 0 -> exp=1 each
    {
        const int cnt = (qi + WIN < 4607 ? qi + WIN : 4607) - 4351;
        if (cnt > 0) lsum += (float)cnt;
    }
    const float linv = 1.0f / lsum;

    // --- write O: lane owns q = r16; 4 consecutive dims per nt ---
#pragma unroll
    for (int nt = 0; nt < 4; nt++) {
        ushort4 o;
        o.x = f2bf(oacc[nt][0] * linv);
        o.y = f2bf(oacc[nt][1] * linv);
        o.z = f2bf(oacc[nt][2] * linv);
        o.w = f2bf(oacc[nt][3] * linv);
        *(ushort4*)&ob[(size_t)og_q * DIM + head * HD + nt * 16 + quad * 4] = o;
    }
}

// ---------------- launch ----------------
extern "C" void kernel_launch(void* const* d_in, const int* in_sizes, int n_in,
                              void* d_out, int out_size, void* d_ws, size_t ws_size,
                              hipStream_t stream) {
    const float* x    = (const float*)d_in[0];
    const float* fcos = (const float*)d_in[1];
    const float* fsin = (const float*)d_in[2];
    const float* wq   = (const float*)d_in[3];
    const float* bq   = (const float*)d_in[4];
    const float* wk   = (const float*)d_in[5];
    const float* bk   = (const float*)d_in[6];
    const float* wv   = (const float*)d_in[7];
    const float* bv   = (const float*)d_in[8];
    const float* wo   = (const float*)d_in[9];
    const float* bo   = (const float*)d_in[10];
    const float* gq   = (const float*)d_in[11];
    const float* gk   = (const float*)d_in[12];

    char* ws = (char*)d_ws;
    unsigned short* xb = (unsigned short*)(ws);
    unsigned short* wt = (unsigned short*)(ws + 17825792);
    unsigned short* h  = (unsigned short*)(ws + 26214400);
    unsigned short* ob = (unsigned short*)(ws + 79691776);
    float* outp = (float*)d_out;

    prep<<<9728, 256, 0, stream>>>(x, xb, wq, wk, wv, wo, wt);
    gemm_bf16<0><<<dim3(68, 8, 3), 256, 0, stream>>>(xb, wt, bq, bk, bv, (void*)h);
    norm_rope<<<dim3(2176, 2), 256, 0, stream>>>(h, h + (size_t)S_ORIG * DIM, gq, gk, fcos, fsin);
    attn<<<dim3(32, 68), 256, 0, stream>>>(h, ob);
    gemm_bf16<1><<<dim3(68, 8, 1), 256, 0, stream>>>(ob, wt + (size_t)3 * DIM * DIM, bo, bo, bo, (void*)outp);
}